// Round 4
// baseline (54333.636 us; speedup 1.0000x reference)
//
#include <hip/hip_runtime.h>

#define B_   256
#define T_   168
#define IN_  64
#define H_   512
#define G_   2048
#define HOR_ 24
#define NB_  512   // persistent grid: 512 blocks x 512 threads = 2 blocks/CU co-resident

typedef unsigned short u16;
typedef unsigned long long u64;
typedef __bf16 bf16x8 __attribute__((ext_vector_type(8)));
typedef float  f32x4  __attribute__((ext_vector_type(4)));

__device__ __forceinline__ u16 f2bf(float f) {
  unsigned u = __float_as_uint(f);
  u += 0x7fffu + ((u >> 16) & 1u);   // round-to-nearest-even
  return (u16)(u >> 16);
}
__device__ __forceinline__ float bf2f(u16 h) {
  return __uint_as_float(((unsigned)h) << 16);
}

// ---------------- split fp32 -> bf16 hi + bf16 lo ----------------
__global__ __launch_bounds__(256) void split_kernel(const float* __restrict__ src,
                                                    u16* __restrict__ hi,
                                                    u16* __restrict__ lo, int n4) {
  int i = blockIdx.x * 256 + threadIdx.x;
  if (i >= n4) return;
  float4 v = ((const float4*)src)[i];
  ushort4 h, l;
  h.x = f2bf(v.x); l.x = f2bf(v.x - bf2f(h.x));
  h.y = f2bf(v.y); l.y = f2bf(v.y - bf2f(h.y));
  h.z = f2bf(v.z); l.z = f2bf(v.z - bf2f(h.z));
  h.w = f2bf(v.w); l.w = f2bf(v.w - bf2f(h.w));
  ((ushort4*)hi)[i] = h;
  ((ushort4*)lo)[i] = l;
}

// ---------------- What = outer(dW0, fcW), split to hi/lo ----------------
__global__ __launch_bounds__(256) void outer_kernel(const float* __restrict__ dW0,
                                                    const float* __restrict__ fcW,
                                                    u16* __restrict__ Wh, u16* __restrict__ Wl) {
  int i = blockIdx.x * 256 + threadIdx.x;   // over 2048*512
  int c = i >> 9, k = i & 511;
  float w = dW0[c] * fcW[k];
  u16 h = f2bf(w);
  Wh[i] = h; Wl[i] = f2bf(w - bf2f(h));
}

// b0p[c] = db0[c] + dW0[c]*fcb
__global__ __launch_bounds__(256) void bias_kernel(const float* __restrict__ db0,
                                                   const float* __restrict__ dW0,
                                                   const float* __restrict__ fcb,
                                                   float* __restrict__ b0p) {
  int i = blockIdx.x * 256 + threadIdx.x;
  if (i < G_) b0p[i] = db0[i] + dW0[i] * fcb[0];
}

// ---------------- hierarchical device-scope grid barrier ----------------
// L1: 64 counters, 8 blocks each (bid&63 keeps members on one XCD under round-robin
// dispatch). L2: 8 counters fed by the 64 L1 leaders. Root fed by 8 L2 leaders.
// Monotone counters, no reset. Bounded spins so a logic bug can't hang the container.
#define BAR_PAD 16   // one 128B line per counter
__device__ __forceinline__ bool gsync(u64* l1, u64* l2, u64* root, int bid, u64 phase) {
  __shared__ int okk;
  __syncthreads();
  __threadfence();   // release: this block's stores visible device-wide
  if (threadIdx.x == 0) {
    int ok = 1;
    const u64 tgt = 8ull * phase;
    const int g = bid & 63;
    long spins;
    __hip_atomic_fetch_add(&l1[g * BAR_PAD], 1ull, __ATOMIC_ACQ_REL, __HIP_MEMORY_SCOPE_AGENT);
    if (bid < 64) {                      // L1 leader of group g==bid
      spins = 0;
      while (__hip_atomic_load(&l1[g * BAR_PAD], __ATOMIC_ACQUIRE, __HIP_MEMORY_SCOPE_AGENT) < tgt) {
        __builtin_amdgcn_s_sleep(1);
        if (++spins > 5000000) { ok = 0; break; }
      }
      __hip_atomic_fetch_add(&l2[(bid & 7) * BAR_PAD], 1ull, __ATOMIC_ACQ_REL, __HIP_MEMORY_SCOPE_AGENT);
      if (bid < 8) {                     // L2 leader
        spins = 0;
        while (__hip_atomic_load(&l2[bid * BAR_PAD], __ATOMIC_ACQUIRE, __HIP_MEMORY_SCOPE_AGENT) < tgt) {
          __builtin_amdgcn_s_sleep(1);
          if (++spins > 5000000) { ok = 0; break; }
        }
        __hip_atomic_fetch_add(root, 1ull, __ATOMIC_ACQ_REL, __HIP_MEMORY_SCOPE_AGENT);
      }
    }
    spins = 0;
    while (__hip_atomic_load(root, __ATOMIC_ACQUIRE, __HIP_MEMORY_SCOPE_AGENT) < tgt) {
      __builtin_amdgcn_s_sleep(2);
      if (++spins > 5000000) { ok = 0; break; }
    }
    okk = ok;
  }
  __syncthreads();
  __threadfence();   // acquire: drop stale L1/L2 lines before reading peers' data
  return okk != 0;
}

// ---------------- one LSTM layer-step job (GEMM + pointwise) ----------------
struct Job {
  const u16 *A1h, *A1l, *W1h, *W1l;
  const u16 *A2h, *A2l, *W2h, *W2l;
  const float* bias;
  float* c; u16 *Hh, *Hl;
  int a1Stride, K1;
};

// 512-thread block: 8 waves = (mb: 16-row half) x (sp: gate strip-pair) x (kh: K-half).
// K-halves reduced through LDS; (sp0,kh0) waves do the pointwise epilogue.
__device__ __forceinline__ void run_job(const Job& J, int bx) {
  const int hc   = bx & 31;          // hcol tile * 16  (hc%8 -> stable XCD home)
  const int mt   = bx >> 5;          // m tile * 32
  const int lane = threadIdx.x & 63;
  const int wave = threadIdx.x >> 6; // 0..7
  const int mb   = wave & 1;
  const int sp   = (wave >> 1) & 1;  // 0 -> gates (i,f), 1 -> (g,o)
  const int kh   = wave >> 2;        // K-half
  const int l16  = lane & 15;
  const int lk   = lane >> 4;
  const int arow = mt * 32 + mb * 16 + l16;
  const int hcb  = hc * 16;
  const int s0   = sp * 2;

  f32x4 acc0 = {0.f, 0.f, 0.f, 0.f};
  f32x4 acc1 = {0.f, 0.f, 0.f, 0.f};

  #pragma unroll 1
  for (int seg = 0; seg < 2; ++seg) {
    const u16 *Ah, *Al, *Wh, *Wl; int K, astr;
    if (seg == 0) {
      K = J.K1; if (K == 0) continue;
      Ah = J.A1h; Al = J.A1l; Wh = J.W1h; Wl = J.W1l; astr = J.a1Stride;
    } else {
      Ah = J.A2h; Al = J.A2l; Wh = J.W2h; Wl = J.W2l; K = 512; astr = 512;
    }
    int kbeg, kend;
    if (K >= 128) { int half = K >> 1; kbeg = kh * half; kend = kbeg + half; }
    else          { kbeg = 0; kend = (kh == 0) ? K : 0; }
    const u16* aph = Ah + (size_t)arow * astr + lk * 8;
    const u16* apl = Al + (size_t)arow * astr + lk * 8;
    const size_t w0 = (size_t)(s0 * 512 + hcb + l16) * K + lk * 8;
    const size_t w1 = (size_t)((s0 + 1) * 512 + hcb + l16) * K + lk * 8;
    const u16 *bh0 = Wh + w0, *bl0 = Wl + w0, *bh1 = Wh + w1, *bl1 = Wl + w1;
    #pragma unroll 1
    for (int k = kbeg; k < kend; k += 64) {   // unroll-2: 12 loads in flight
      bf16x8 ahA  = *(const bf16x8*)(aph + k);
      bf16x8 alA  = *(const bf16x8*)(apl + k);
      bf16x8 p0hA = *(const bf16x8*)(bh0 + k);
      bf16x8 p0lA = *(const bf16x8*)(bl0 + k);
      bf16x8 p1hA = *(const bf16x8*)(bh1 + k);
      bf16x8 p1lA = *(const bf16x8*)(bl1 + k);
      bf16x8 ahB  = *(const bf16x8*)(aph + k + 32);
      bf16x8 alB  = *(const bf16x8*)(apl + k + 32);
      bf16x8 p0hB = *(const bf16x8*)(bh0 + k + 32);
      bf16x8 p0lB = *(const bf16x8*)(bl0 + k + 32);
      bf16x8 p1hB = *(const bf16x8*)(bh1 + k + 32);
      bf16x8 p1lB = *(const bf16x8*)(bl1 + k + 32);
      acc0 = __builtin_amdgcn_mfma_f32_16x16x32_bf16(ahA, p0hA, acc0, 0, 0, 0);
      acc1 = __builtin_amdgcn_mfma_f32_16x16x32_bf16(ahA, p1hA, acc1, 0, 0, 0);
      acc0 = __builtin_amdgcn_mfma_f32_16x16x32_bf16(ahA, p0lA, acc0, 0, 0, 0);
      acc1 = __builtin_amdgcn_mfma_f32_16x16x32_bf16(ahA, p1lA, acc1, 0, 0, 0);
      acc0 = __builtin_amdgcn_mfma_f32_16x16x32_bf16(alA, p0hA, acc0, 0, 0, 0);
      acc1 = __builtin_amdgcn_mfma_f32_16x16x32_bf16(alA, p1hA, acc1, 0, 0, 0);
      acc0 = __builtin_amdgcn_mfma_f32_16x16x32_bf16(ahB, p0hB, acc0, 0, 0, 0);
      acc1 = __builtin_amdgcn_mfma_f32_16x16x32_bf16(ahB, p1hB, acc1, 0, 0, 0);
      acc0 = __builtin_amdgcn_mfma_f32_16x16x32_bf16(ahB, p0lB, acc0, 0, 0, 0);
      acc1 = __builtin_amdgcn_mfma_f32_16x16x32_bf16(ahB, p1lB, acc1, 0, 0, 0);
      acc0 = __builtin_amdgcn_mfma_f32_16x16x32_bf16(alB, p0hB, acc0, 0, 0, 0);
      acc1 = __builtin_amdgcn_mfma_f32_16x16x32_bf16(alB, p1hB, acc1, 0, 0, 0);
    }
  }

  // K-half + strip exchange. Slots: (sp0,kh1)->0,1  (sp1,kh0)->2,3  (sp1,kh1)->4,5
  // Row stride 17 floats breaks the 4-way bank conflict of stride-16.
  __shared__ float xch[6][2][16][17];
  if (sp | kh) {
    const int ws = (sp * 2 + kh) * 2 - 2;
    #pragma unroll
    for (int r = 0; r < 4; ++r) {
      xch[ws][mb][lk * 4 + r][l16]     = acc0[r];
      xch[ws + 1][mb][lk * 4 + r][l16] = acc1[r];
    }
  }
  __syncthreads();
  if (sp == 0 && kh == 0) {
    const int hcol = hcb + l16;
    const float bi = J.bias[hcol];
    const float bf = J.bias[512 + hcol];
    const float bg = J.bias[1024 + hcol];
    const float bo = J.bias[1536 + hcol];
    #pragma unroll
    for (int r = 0; r < 4; ++r) {
      const int rr = lk * 4 + r;
      const int row = mt * 32 + mb * 16 + rr;
      const size_t idx = (size_t)row * 512 + hcol;
      float gi = acc0[r] + xch[0][mb][rr][l16] + bi;
      float gf = acc1[r] + xch[1][mb][rr][l16] + bf;
      float gg = xch[2][mb][rr][l16] + xch[4][mb][rr][l16] + bg;
      float go = xch[3][mb][rr][l16] + xch[5][mb][rr][l16] + bo;
      float si = 1.f / (1.f + expf(-gi));
      float sf = 1.f / (1.f + expf(-gf));
      float so = 1.f / (1.f + expf(-go));
      float cn = sf * J.c[idx] + si * tanhf(gg);
      float hn = so * tanhf(cn);
      J.c[idx] = cn;
      u16 hh = f2bf(hn);
      J.Hh[idx] = hh;
      J.Hl[idx] = f2bf(hn - bf2f(hh));
    }
  }
  __syncthreads();
}

// fc for 32 rows per designated block (8 blocks cover B=256)
__device__ __forceinline__ void fc_block(const u16* Hh, const u16* Hl,
                                         const float* fcW, const float* fcb,
                                         float* dout, int step, int b2) {
  int tid = threadIdx.x;
  int r = b2 * 32 + (tid >> 4);
  int cc = tid & 15;
  float s = 0.f;
  int k0 = cc * 32;
  for (int k = k0; k < k0 + 32; ++k) {
    float h = bf2f(Hh[(size_t)r * 512 + k]) + bf2f(Hl[(size_t)r * 512 + k]);
    s += h * fcW[k];
  }
  for (int off = 8; off; off >>= 1) s += __shfl_down(s, off, 16);
  if (cc == 0) dout[(size_t)r * HOR_ + step] = s + fcb[0];
}

// ---------------- persistent mega kernel ----------------
struct MegaParams {
  const u16 *xh, *xl;
  const u16 *eW0h, *eW0l, *eU0h, *eU0l, *eW1h, *eW1l, *eU1h, *eU1l;
  const u16 *dU0h, *dU0l, *dW1h, *dW1l, *dU1h, *dU1l, *Whh, *Whl;
  const float *eb0, *eb1, *db0, *db1, *b0p, *fcW, *fcb;
  u16 *h0hA, *h0lA, *h0hB, *h0lB, *h1hA, *h1lA, *h1hB, *h1lB;
  float *c0, *c1, *dout;
  u64 *barL1, *barL2, *barRoot;
};

__global__ __launch_bounds__(512, 4) void mega_kernel(MegaParams P) {
  const int bid = blockIdx.x;
  u64 phase = 0;
  int c0i = 0, c1i = 0;
  u16* h0h[2] = {P.h0hA, P.h0hB}; u16* h0l[2] = {P.h0lA, P.h0lB};
  u16* h1h[2] = {P.h1hA, P.h1hB}; u16* h1l[2] = {P.h1lA, P.h1lB};

  // ---------- encoder: fused (layer0 step t) + (layer1 step t-1) ----------
  for (int t = 0; t <= T_; ++t) {
    if (bid < 256) {
      if (t < T_) {
        Job J;
        J.A1h = P.xh + (size_t)t * IN_; J.A1l = P.xl + (size_t)t * IN_;
        J.a1Stride = T_ * IN_; J.K1 = IN_;
        J.W1h = P.eW0h; J.W1l = P.eW0l;
        J.A2h = h0h[c0i]; J.A2l = h0l[c0i]; J.W2h = P.eU0h; J.W2l = P.eU0l;
        J.bias = P.eb0; J.c = P.c0; J.Hh = h0h[1 - c0i]; J.Hl = h0l[1 - c0i];
        run_job(J, bid);
      }
    } else {
      if (t >= 1) {
        Job J;
        J.A1h = h0h[c0i]; J.A1l = h0l[c0i]; J.a1Stride = 512; J.K1 = 512;
        J.W1h = P.eW1h; J.W1l = P.eW1l;
        J.A2h = h1h[c1i]; J.A2l = h1l[c1i]; J.W2h = P.eU1h; J.W2l = P.eU1l;
        J.bias = P.eb1; J.c = P.c1; J.Hh = h1h[1 - c1i]; J.Hl = h1l[1 - c1i];
        run_job(J, bid - 256);
      }
    }
    if (!gsync(P.barL1, P.barL2, P.barRoot, bid, ++phase)) return;
    if (t < T_) c0i ^= 1;
    if (t >= 1) c1i ^= 1;
  }

  // ---------- decoder: fc folded into L0 via What; fc output piggybacked ----------
  for (int s = 0; s < HOR_; ++s) {
    if (bid < 256) {
      Job J;
      J.A1h = h1h[c1i]; J.A1l = h1l[c1i]; J.a1Stride = 512; J.K1 = (s == 0 ? 0 : 512);
      J.W1h = P.Whh; J.W1l = P.Whl;
      J.A2h = h0h[c0i]; J.A2l = h0l[c0i]; J.W2h = P.dU0h; J.W2l = P.dU0l;
      J.bias = (s == 0 ? P.db0 : P.b0p); J.c = P.c0;
      J.Hh = h0h[1 - c0i]; J.Hl = h0l[1 - c0i];
      run_job(J, bid);
    } else if (bid >= 256 && bid < 264 && s >= 1) {
      fc_block(h1h[c1i], h1l[c1i], P.fcW, P.fcb, P.dout, s - 1, bid - 256);
    }
    if (!gsync(P.barL1, P.barL2, P.barRoot, bid, ++phase)) return;
    c0i ^= 1;

    if (bid < 256) {
      Job J;
      J.A1h = h0h[c0i]; J.A1l = h0l[c0i]; J.a1Stride = 512; J.K1 = 512;
      J.W1h = P.dW1h; J.W1l = P.dW1l;
      J.A2h = h1h[c1i]; J.A2l = h1l[c1i]; J.W2h = P.dU1h; J.W2l = P.dU1l;
      J.bias = P.db1; J.c = P.c1; J.Hh = h1h[1 - c1i]; J.Hl = h1l[1 - c1i];
      run_job(J, bid);
    }
    if (!gsync(P.barL1, P.barL2, P.barRoot, bid, ++phase)) return;
    c1i ^= 1;
  }
  if (bid >= 256 && bid < 264)
    fc_block(h1h[c1i], h1l[c1i], P.fcW, P.fcb, P.dout, HOR_ - 1, bid - 256);
}

// ---------------- host ----------------
extern "C" void kernel_launch(void* const* d_in, const int* in_sizes, int n_in,
                              void* d_out, int out_size, void* d_ws, size_t ws_size,
                              hipStream_t stream) {
  const float* x   = (const float*)d_in[0];
  const float* eW0 = (const float*)d_in[2];
  const float* eU0 = (const float*)d_in[3];
  const float* eb0 = (const float*)d_in[4];
  const float* eW1 = (const float*)d_in[5];
  const float* eU1 = (const float*)d_in[6];
  const float* eb1 = (const float*)d_in[7];
  const float* dW0 = (const float*)d_in[8];
  const float* dU0 = (const float*)d_in[9];
  const float* db0 = (const float*)d_in[10];
  const float* dW1 = (const float*)d_in[11];
  const float* dU1 = (const float*)d_in[12];
  const float* db1 = (const float*)d_in[13];
  const float* fcW = (const float*)d_in[14];
  const float* fcb = (const float*)d_in[15];
  float* dout = (float*)d_out;

  char* base = (char*)d_ws;
  size_t off = 0;
  auto alloc = [&](size_t bytes) -> char* {
    char* p = base + off;
    off = (off + bytes + 255) & ~(size_t)255;
    return p;
  };

  const size_t nx  = (size_t)B_ * T_ * IN_;
  const size_t nW0 = (size_t)G_ * IN_;
  const size_t nWH = (size_t)G_ * H_;
  u16* xhi = (u16*)alloc(nx * 2);
  u16* xlo = (u16*)alloc(nx * 2);
  u16 *eW0h = (u16*)alloc(nW0 * 2), *eW0l = (u16*)alloc(nW0 * 2);
  u16 *eU0h = (u16*)alloc(nWH * 2), *eU0l = (u16*)alloc(nWH * 2);
  u16 *eW1h = (u16*)alloc(nWH * 2), *eW1l = (u16*)alloc(nWH * 2);
  u16 *eU1h = (u16*)alloc(nWH * 2), *eU1l = (u16*)alloc(nWH * 2);
  u16 *dU0h = (u16*)alloc(nWH * 2), *dU0l = (u16*)alloc(nWH * 2);
  u16 *dW1h = (u16*)alloc(nWH * 2), *dW1l = (u16*)alloc(nWH * 2);
  u16 *dU1h = (u16*)alloc(nWH * 2), *dU1l = (u16*)alloc(nWH * 2);
  u16 *Whh  = (u16*)alloc(nWH * 2), *Whl  = (u16*)alloc(nWH * 2);
  float* b0p = (float*)alloc(G_ * 4);

  // zero-initialized state region (memset below)
  char* zbase = base + off;
  const size_t nh = (size_t)B_ * H_;
  u16 *h0hA = (u16*)alloc(nh * 2), *h0lA = (u16*)alloc(nh * 2);
  u16 *h0hB = (u16*)alloc(nh * 2), *h0lB = (u16*)alloc(nh * 2);
  u16 *h1hA = (u16*)alloc(nh * 2), *h1lA = (u16*)alloc(nh * 2);
  u16 *h1hB = (u16*)alloc(nh * 2), *h1lB = (u16*)alloc(nh * 2);
  float* c0 = (float*)alloc(nh * 4);
  float* c1 = (float*)alloc(nh * 4);
  u64* barL1   = (u64*)alloc(64 * BAR_PAD * 8);
  u64* barL2   = (u64*)alloc(8 * BAR_PAD * 8);
  u64* barRoot = (u64*)alloc(128);
  size_t zbytes = (size_t)((base + off) - zbase);
  (void)ws_size; (void)in_sizes; (void)n_in; (void)out_size;

  hipMemsetAsync(zbase, 0, zbytes, stream);

  auto split = [&](const float* s, u16* h, u16* l, size_t n) {
    int n4 = (int)(n / 4);
    split_kernel<<<dim3((n4 + 255) / 256), dim3(256), 0, stream>>>(s, h, l, n4);
  };
  split(x, xhi, xlo, nx);
  split(eW0, eW0h, eW0l, nW0);
  split(eU0, eU0h, eU0l, nWH);
  split(eW1, eW1h, eW1l, nWH);
  split(eU1, eU1h, eU1l, nWH);
  split(dU0, dU0h, dU0l, nWH);
  split(dW1, dW1h, dW1l, nWH);
  split(dU1, dU1h, dU1l, nWH);
  outer_kernel<<<dim3((int)(nWH / 256)), dim3(256), 0, stream>>>(dW0, fcW, Whh, Whl);
  bias_kernel<<<dim3((G_ + 255) / 256), dim3(256), 0, stream>>>(db0, dW0, fcb, b0p);

  MegaParams P;
  P.xh = xhi; P.xl = xlo;
  P.eW0h = eW0h; P.eW0l = eW0l; P.eU0h = eU0h; P.eU0l = eU0l;
  P.eW1h = eW1h; P.eW1l = eW1l; P.eU1h = eU1h; P.eU1l = eU1l;
  P.dU0h = dU0h; P.dU0l = dU0l; P.dW1h = dW1h; P.dW1l = dW1l;
  P.dU1h = dU1h; P.dU1l = dU1l; P.Whh = Whh; P.Whl = Whl;
  P.eb0 = eb0; P.eb1 = eb1; P.db0 = db0; P.db1 = db1; P.b0p = b0p;
  P.fcW = fcW; P.fcb = fcb;
  P.h0hA = h0hA; P.h0lA = h0lA; P.h0hB = h0hB; P.h0lB = h0lB;
  P.h1hA = h1hA; P.h1lA = h1lA; P.h1hB = h1hB; P.h1lB = h1lB;
  P.c0 = c0; P.c1 = c1; P.dout = dout;
  P.barL1 = barL1; P.barL2 = barL2; P.barRoot = barRoot;

  mega_kernel<<<dim3(NB_), dim3(512), 0, stream>>>(P);
}

// Round 5
// 7857.538 us; speedup vs baseline: 6.9148x; 6.9148x over previous
//
#include <hip/hip_runtime.h>

#define B_   256
#define T_   168
#define IN_  64
#define H_   512
#define G_   2048
#define HOR_ 24

typedef unsigned short u16;
typedef __bf16 bf16x8 __attribute__((ext_vector_type(8)));
typedef float  f32x4  __attribute__((ext_vector_type(4)));

__device__ __forceinline__ u16 f2bf(float f) {
  unsigned u = __float_as_uint(f);
  u += 0x7fffu + ((u >> 16) & 1u);   // round-to-nearest-even
  return (u16)(u >> 16);
}
__device__ __forceinline__ float bf2f(u16 h) {
  return __uint_as_float(((unsigned)h) << 16);
}

// ---------------- split fp32 -> bf16 hi + bf16 lo ----------------
__global__ __launch_bounds__(256) void split_kernel(const float* __restrict__ src,
                                                    u16* __restrict__ hi,
                                                    u16* __restrict__ lo, int n4) {
  int i = blockIdx.x * 256 + threadIdx.x;
  if (i >= n4) return;
  float4 v = ((const float4*)src)[i];
  ushort4 h, l;
  h.x = f2bf(v.x); l.x = f2bf(v.x - bf2f(h.x));
  h.y = f2bf(v.y); l.y = f2bf(v.y - bf2f(h.y));
  h.z = f2bf(v.z); l.z = f2bf(v.z - bf2f(h.z));
  h.w = f2bf(v.w); l.w = f2bf(v.w - bf2f(h.w));
  ((ushort4*)hi)[i] = h;
  ((ushort4*)lo)[i] = l;
}

// ---------------- What = outer(dW0, fcW), split to hi/lo ----------------
__global__ __launch_bounds__(256) void outer_kernel(const float* __restrict__ dW0,
                                                    const float* __restrict__ fcW,
                                                    u16* __restrict__ Wh, u16* __restrict__ Wl) {
  int i = blockIdx.x * 256 + threadIdx.x;   // over 2048*512
  int c = i >> 9, k = i & 511;
  float w = dW0[c] * fcW[k];
  u16 h = f2bf(w);
  Wh[i] = h; Wl[i] = f2bf(w - bf2f(h));
}

// b0p[c] = db0[c] + dW0[c]*fcb
__global__ __launch_bounds__(256) void bias_kernel(const float* __restrict__ db0,
                                                   const float* __restrict__ dW0,
                                                   const float* __restrict__ fcb,
                                                   float* __restrict__ b0p) {
  int i = blockIdx.x * 256 + threadIdx.x;
  if (i < G_) b0p[i] = db0[i] + dW0[i] * fcb[0];
}

// ---------------- one LSTM layer-step job (GEMM + pointwise) ----------------
struct Job {
  const u16 *A1h, *A1l, *W1h, *W1l;
  const u16 *A2h, *A2l, *W2h, *W2l;
  const float* bias;
  float* c; u16 *Hh, *Hl;
  int a1Stride, K1;
};

// 512-thread block: 8 waves = (mb: 16-row half) x (sp: gate strip-pair) x (kh: K-half).
// K-halves reduced through LDS; (sp0,kh0) waves do the pointwise epilogue.
__device__ __forceinline__ void run_job(const Job& J, int bx) {
  const int hc   = bx & 31;          // hcol tile * 16  (hc%8 -> stable XCD home)
  const int mt   = bx >> 5;          // m tile * 32
  const int lane = threadIdx.x & 63;
  const int wave = threadIdx.x >> 6; // 0..7
  const int mb   = wave & 1;
  const int sp   = (wave >> 1) & 1;  // 0 -> gates (i,f), 1 -> (g,o)
  const int kh   = wave >> 2;        // K-half
  const int l16  = lane & 15;
  const int lk   = lane >> 4;
  const int arow = mt * 32 + mb * 16 + l16;
  const int hcb  = hc * 16;
  const int s0   = sp * 2;

  f32x4 acc0 = {0.f, 0.f, 0.f, 0.f};
  f32x4 acc1 = {0.f, 0.f, 0.f, 0.f};

  #pragma unroll 1
  for (int seg = 0; seg < 2; ++seg) {
    const u16 *Ah, *Al, *Wh, *Wl; int K, astr;
    if (seg == 0) {
      K = J.K1; if (K == 0) continue;
      Ah = J.A1h; Al = J.A1l; Wh = J.W1h; Wl = J.W1l; astr = J.a1Stride;
    } else {
      Ah = J.A2h; Al = J.A2l; Wh = J.W2h; Wl = J.W2l; K = 512; astr = 512;
    }
    int kbeg, kend;
    if (K >= 128) { int half = K >> 1; kbeg = kh * half; kend = kbeg + half; }
    else          { kbeg = 0; kend = (kh == 0) ? K : 0; }
    const u16* aph = Ah + (size_t)arow * astr + lk * 8;
    const u16* apl = Al + (size_t)arow * astr + lk * 8;
    const size_t w0 = (size_t)(s0 * 512 + hcb + l16) * K + lk * 8;
    const size_t w1 = (size_t)((s0 + 1) * 512 + hcb + l16) * K + lk * 8;
    const u16 *bh0 = Wh + w0, *bl0 = Wl + w0, *bh1 = Wh + w1, *bl1 = Wl + w1;
    #pragma unroll 1
    for (int k = kbeg; k < kend; k += 64) {   // unroll-2: 12 loads in flight
      bf16x8 ahA  = *(const bf16x8*)(aph + k);
      bf16x8 alA  = *(const bf16x8*)(apl + k);
      bf16x8 p0hA = *(const bf16x8*)(bh0 + k);
      bf16x8 p0lA = *(const bf16x8*)(bl0 + k);
      bf16x8 p1hA = *(const bf16x8*)(bh1 + k);
      bf16x8 p1lA = *(const bf16x8*)(bl1 + k);
      bf16x8 ahB  = *(const bf16x8*)(aph + k + 32);
      bf16x8 alB  = *(const bf16x8*)(apl + k + 32);
      bf16x8 p0hB = *(const bf16x8*)(bh0 + k + 32);
      bf16x8 p0lB = *(const bf16x8*)(bl0 + k + 32);
      bf16x8 p1hB = *(const bf16x8*)(bh1 + k + 32);
      bf16x8 p1lB = *(const bf16x8*)(bl1 + k + 32);
      acc0 = __builtin_amdgcn_mfma_f32_16x16x32_bf16(ahA, p0hA, acc0, 0, 0, 0);
      acc1 = __builtin_amdgcn_mfma_f32_16x16x32_bf16(ahA, p1hA, acc1, 0, 0, 0);
      acc0 = __builtin_amdgcn_mfma_f32_16x16x32_bf16(ahA, p0lA, acc0, 0, 0, 0);
      acc1 = __builtin_amdgcn_mfma_f32_16x16x32_bf16(ahA, p1lA, acc1, 0, 0, 0);
      acc0 = __builtin_amdgcn_mfma_f32_16x16x32_bf16(alA, p0hA, acc0, 0, 0, 0);
      acc1 = __builtin_amdgcn_mfma_f32_16x16x32_bf16(alA, p1hA, acc1, 0, 0, 0);
      acc0 = __builtin_amdgcn_mfma_f32_16x16x32_bf16(ahB, p0hB, acc0, 0, 0, 0);
      acc1 = __builtin_amdgcn_mfma_f32_16x16x32_bf16(ahB, p1hB, acc1, 0, 0, 0);
      acc0 = __builtin_amdgcn_mfma_f32_16x16x32_bf16(ahB, p0lB, acc0, 0, 0, 0);
      acc1 = __builtin_amdgcn_mfma_f32_16x16x32_bf16(ahB, p1lB, acc1, 0, 0, 0);
      acc0 = __builtin_amdgcn_mfma_f32_16x16x32_bf16(alB, p0hB, acc0, 0, 0, 0);
      acc1 = __builtin_amdgcn_mfma_f32_16x16x32_bf16(alB, p1hB, acc1, 0, 0, 0);
    }
  }

  // K-half + strip exchange. Slots: (sp0,kh1)->0,1  (sp1,kh0)->2,3  (sp1,kh1)->4,5
  // Row stride 17 floats breaks the 4-way bank conflict of stride-16.
  __shared__ float xch[6][2][16][17];
  if (sp | kh) {
    const int ws = (sp * 2 + kh) * 2 - 2;
    #pragma unroll
    for (int r = 0; r < 4; ++r) {
      xch[ws][mb][lk * 4 + r][l16]     = acc0[r];
      xch[ws + 1][mb][lk * 4 + r][l16] = acc1[r];
    }
  }
  __syncthreads();
  if (sp == 0 && kh == 0) {
    const int hcol = hcb + l16;
    const float bi = J.bias[hcol];
    const float bf = J.bias[512 + hcol];
    const float bg = J.bias[1024 + hcol];
    const float bo = J.bias[1536 + hcol];
    #pragma unroll
    for (int r = 0; r < 4; ++r) {
      const int rr = lk * 4 + r;
      const int row = mt * 32 + mb * 16 + rr;
      const size_t idx = (size_t)row * 512 + hcol;
      float gi = acc0[r] + xch[0][mb][rr][l16] + bi;
      float gf = acc1[r] + xch[1][mb][rr][l16] + bf;
      float gg = xch[2][mb][rr][l16] + xch[4][mb][rr][l16] + bg;
      float go = xch[3][mb][rr][l16] + xch[5][mb][rr][l16] + bo;
      float si = 1.f / (1.f + expf(-gi));
      float sf = 1.f / (1.f + expf(-gf));
      float so = 1.f / (1.f + expf(-go));
      float cn = sf * J.c[idx] + si * tanhf(gg);
      float hn = so * tanhf(cn);
      J.c[idx] = cn;
      u16 hh = f2bf(hn);
      J.Hh[idx] = hh;
      J.Hl[idx] = f2bf(hn - bf2f(hh));
    }
  }
}

// fc for 32 rows per block (8 blocks cover B=256); 512 threads
__device__ __forceinline__ void fc_block(const u16* Hh, const u16* Hl,
                                         const float* fcW, const float* fcb,
                                         float* dout, int step, int b2) {
  int tid = threadIdx.x;
  int r = b2 * 32 + (tid >> 4);
  int cc = tid & 15;
  float s = 0.f;
  int k0 = cc * 32;
  for (int k = k0; k < k0 + 32; ++k) {
    float h = bf2f(Hh[(size_t)r * 512 + k]) + bf2f(Hl[(size_t)r * 512 + k]);
    s += h * fcW[k];
  }
  for (int off = 8; off; off >>= 1) s += __shfl_down(s, off, 16);
  if (cc == 0) dout[(size_t)r * HOR_ + step] = s + fcb[0];
}

// ---------------- step kernel: njobs GEMM-jobs + optional piggy-backed fc ----------------
struct StepParams {
  Job job[2];
  int njobs;
  const u16 *fcHh, *fcHl;
  const float *fcW, *fcb;
  float* dout;
  int fcStep;      // -1 = disabled
};

__global__ __launch_bounds__(512, 4) void lstm_step_kernel(StepParams p) {
  const int bid = blockIdx.x;
  const int jb  = p.njobs << 8;
  if (bid < jb) {
    run_job(p.job[bid >> 8], bid & 255);
  } else if (p.fcStep >= 0) {
    fc_block(p.fcHh, p.fcHl, p.fcW, p.fcb, p.dout, p.fcStep, bid - jb);
  }
}

// ---------------- host ----------------
extern "C" void kernel_launch(void* const* d_in, const int* in_sizes, int n_in,
                              void* d_out, int out_size, void* d_ws, size_t ws_size,
                              hipStream_t stream) {
  const float* x   = (const float*)d_in[0];
  const float* eW0 = (const float*)d_in[2];
  const float* eU0 = (const float*)d_in[3];
  const float* eb0 = (const float*)d_in[4];
  const float* eW1 = (const float*)d_in[5];
  const float* eU1 = (const float*)d_in[6];
  const float* eb1 = (const float*)d_in[7];
  const float* dW0 = (const float*)d_in[8];
  const float* dU0 = (const float*)d_in[9];
  const float* db0 = (const float*)d_in[10];
  const float* dW1 = (const float*)d_in[11];
  const float* dU1 = (const float*)d_in[12];
  const float* db1 = (const float*)d_in[13];
  const float* fcW = (const float*)d_in[14];
  const float* fcb = (const float*)d_in[15];
  float* dout = (float*)d_out;

  char* base = (char*)d_ws;
  size_t off = 0;
  auto alloc = [&](size_t bytes) -> char* {
    char* p = base + off;
    off = (off + bytes + 255) & ~(size_t)255;
    return p;
  };

  const size_t nx  = (size_t)B_ * T_ * IN_;
  const size_t nW0 = (size_t)G_ * IN_;
  const size_t nWH = (size_t)G_ * H_;
  u16* xhi = (u16*)alloc(nx * 2);
  u16* xlo = (u16*)alloc(nx * 2);
  u16 *eW0h = (u16*)alloc(nW0 * 2), *eW0l = (u16*)alloc(nW0 * 2);
  u16 *eU0h = (u16*)alloc(nWH * 2), *eU0l = (u16*)alloc(nWH * 2);
  u16 *eW1h = (u16*)alloc(nWH * 2), *eW1l = (u16*)alloc(nWH * 2);
  u16 *eU1h = (u16*)alloc(nWH * 2), *eU1l = (u16*)alloc(nWH * 2);
  u16 *dU0h = (u16*)alloc(nWH * 2), *dU0l = (u16*)alloc(nWH * 2);
  u16 *dW1h = (u16*)alloc(nWH * 2), *dW1l = (u16*)alloc(nWH * 2);
  u16 *dU1h = (u16*)alloc(nWH * 2), *dU1l = (u16*)alloc(nWH * 2);
  u16 *Whh  = (u16*)alloc(nWH * 2), *Whl  = (u16*)alloc(nWH * 2);
  float* b0p = (float*)alloc(G_ * 4);

  // zero-initialized state region (memset below)
  char* zbase = base + off;
  const size_t nh = (size_t)B_ * H_;
  u16 *h0h[2], *h0l[2], *h1h[2], *h1l[2];
  for (int i = 0; i < 2; ++i) { h0h[i] = (u16*)alloc(nh * 2); h0l[i] = (u16*)alloc(nh * 2); }
  for (int i = 0; i < 2; ++i) { h1h[i] = (u16*)alloc(nh * 2); h1l[i] = (u16*)alloc(nh * 2); }
  float* c0 = (float*)alloc(nh * 4);
  float* c1 = (float*)alloc(nh * 4);
  size_t zbytes = (size_t)((base + off) - zbase);
  (void)ws_size; (void)in_sizes; (void)n_in; (void)out_size;

  hipMemsetAsync(zbase, 0, zbytes, stream);

  auto split = [&](const float* s, u16* h, u16* l, size_t n) {
    int n4 = (int)(n / 4);
    split_kernel<<<dim3((n4 + 255) / 256), dim3(256), 0, stream>>>(s, h, l, n4);
  };
  split(x, xhi, xlo, nx);
  split(eW0, eW0h, eW0l, nW0);
  split(eU0, eU0h, eU0l, nWH);
  split(eW1, eW1h, eW1l, nWH);
  split(eU1, eU1h, eU1l, nWH);
  split(dU0, dU0h, dU0l, nWH);
  split(dW1, dW1h, dW1l, nWH);
  split(dU1, dU1h, dU1l, nWH);
  outer_kernel<<<dim3((int)(nWH / 256)), dim3(256), 0, stream>>>(dW0, fcW, Whh, Whl);
  bias_kernel<<<dim3((G_ + 255) / 256), dim3(256), 0, stream>>>(db0, dW0, fcb, b0p);

  int c0i = 0, c1i = 0;

  auto launch = [&](StepParams& P) {
    int grid = P.njobs * 256 + (P.fcStep >= 0 ? 8 : 0);
    lstm_step_kernel<<<dim3(grid), dim3(512), 0, stream>>>(P);
  };

  // ---------- encoder: fused (layer0 step t) + (layer1 step t-1) ----------
  for (int t = 0; t <= T_; ++t) {
    StepParams P; P.njobs = 0; P.fcStep = -1;
    if (t < T_) {
      Job j{};
      j.A1h = xhi + (size_t)t * IN_; j.A1l = xlo + (size_t)t * IN_;
      j.a1Stride = T_ * IN_; j.K1 = IN_;
      j.W1h = eW0h; j.W1l = eW0l;
      j.A2h = h0h[c0i]; j.A2l = h0l[c0i]; j.W2h = eU0h; j.W2l = eU0l;
      j.bias = eb0; j.c = c0; j.Hh = h0h[1 - c0i]; j.Hl = h0l[1 - c0i];
      P.job[P.njobs++] = j;
    }
    if (t >= 1) {
      Job j{};
      j.A1h = h0h[c0i]; j.A1l = h0l[c0i]; j.a1Stride = 512; j.K1 = 512;
      j.W1h = eW1h; j.W1l = eW1l;
      j.A2h = h1h[c1i]; j.A2l = h1l[c1i]; j.W2h = eU1h; j.W2l = eU1l;
      j.bias = eb1; j.c = c1; j.Hh = h1h[1 - c1i]; j.Hl = h1l[1 - c1i];
      P.job[P.njobs++] = j;
    }
    launch(P);
    if (t < T_) c0i ^= 1;
    if (t >= 1) c1i ^= 1;
  }

  // ---------- decoder: fc folded into L0 via What; fc output piggybacked ----------
  for (int s = 0; s < HOR_; ++s) {
    {
      StepParams P; P.njobs = 1; P.fcStep = -1;
      Job j{};
      j.A1h = h1h[c1i]; j.A1l = h1l[c1i]; j.a1Stride = 512; j.K1 = (s == 0 ? 0 : 512);
      j.W1h = Whh; j.W1l = Whl;
      j.A2h = h0h[c0i]; j.A2l = h0l[c0i]; j.W2h = dU0h; j.W2l = dU0l;
      j.bias = (s == 0 ? db0 : b0p); j.c = c0;
      j.Hh = h0h[1 - c0i]; j.Hl = h0l[1 - c0i];
      P.job[0] = j;
      if (s >= 1) {   // fc for step s-1 on the stable h1[c1i]
        P.fcStep = s - 1; P.fcHh = h1h[c1i]; P.fcHl = h1l[c1i];
        P.fcW = fcW; P.fcb = fcb; P.dout = dout;
      }
      launch(P);
      c0i ^= 1;
    }
    {
      StepParams P; P.njobs = 1; P.fcStep = -1;
      Job j{};
      j.A1h = h0h[c0i]; j.A1l = h0l[c0i]; j.a1Stride = 512; j.K1 = 512;
      j.W1h = dW1h; j.W1l = dW1l;
      j.A2h = h1h[c1i]; j.A2l = h1l[c1i]; j.W2h = dU1h; j.W2l = dU1l;
      j.bias = db1; j.c = c1; j.Hh = h1h[1 - c1i]; j.Hl = h1l[1 - c1i];
      P.job[0] = j;
      launch(P);
      c1i ^= 1;
    }
  }
  // final fc for step 23
  {
    StepParams P; P.njobs = 0;
    P.fcStep = HOR_ - 1; P.fcHh = h1h[c1i]; P.fcHl = h1l[c1i];
    P.fcW = fcW; P.fcb = fcb; P.dout = dout;
    launch(P);
  }
}